// Round 11
// baseline (172.291 us; speedup 1.0000x reference)
//
#include <hip/hip_runtime.h>
#include <hip/hip_bf16.h>
#include <math.h>

#define DT (1.0f / 60.0f)

typedef __bf16 bf16x8 __attribute__((ext_vector_type(8)));
typedef float f32x4 __attribute__((ext_vector_type(4)));

#define XSTRIDE 848   // x rows (row-major): 212 dwords % 8 == 4 -> 2-way (free)
#define HSTRIDE 1040  // h rows (row-major): 260 dwords % 8 == 4 -> 2-way (free)
#define ROWS 32       // batch rows per block
#define SLAB 33280    // one slab: 32 x 1040 (h) = 32 x 260 f32 (out) >= 32 x 848 (x)

// 4-byte-aligned float4 for vectorized loads of 13-float-strided state
struct __attribute__((packed)) f4u {
    float x, y, z, w;
};

// ---------------------------------------------------------------------------
// Weight prep into MFMA-fragment-packed layout.
// frag(ks, nt) is 1KB contiguous; lane l (lrow=l&15, kgrp=l>>4) reads bytes
// [l*16, +16) = W[k = ks*32 + kgrp*8 + e][n = nt*16 + lrow], e=0..7.
// ---------------------------------------------------------------------------
__global__ __launch_bounds__(256) void prep_weights(
    const float* __restrict__ W1, const float* __restrict__ W2,
    const float* __restrict__ W3, __hip_bfloat16* __restrict__ W1p,
    __hip_bfloat16* __restrict__ W2p, __hip_bfloat16* __restrict__ W3p) {
    int idx = blockIdx.x * 256 + threadIdx.x;
    if (idx < 212992) {  // W1p: KS=13, NT=32 (K pad 416, N=512)
        int d = idx;
        int e = d & 7, l = (d >> 3) & 63, t = d >> 9;
        int nt = t & 31, ks = t >> 5;
        int n = nt * 16 + (l & 15);
        int k = ks * 32 + (l >> 4) * 8 + e;
        W1p[d] = __float2bfloat16(k < 414 ? W1[k * 512 + n] : 0.0f);
        return;
    }
    idx -= 212992;
    if (idx < 262144) {  // W2p: KS=16, NT=32
        int d = idx;
        int e = d & 7, l = (d >> 3) & 63, t = d >> 9;
        int nt = t & 31, ks = t >> 5;
        int n = nt * 16 + (l & 15);
        int k = ks * 32 + (l >> 4) * 8 + e;
        W2p[d] = __float2bfloat16(W2[k * 512 + n]);
        return;
    }
    idx -= 262144;
    if (idx < 65536) {  // W3p: KS=16, NT=8 (N pad 128)
        int d = idx;
        int e = d & 7, l = (d >> 3) & 63, t = d >> 9;
        int nt = t & 7, ks = t >> 3;
        int n = nt * 16 + (l & 15);
        int k = ks * 32 + (l >> 4) * 8 + e;
        W3p[d] = __float2bfloat16(n < 120 ? W3[k * 120 + n] : 0.0f);
    }
}

// ---------------------------------------------------------------------------
// K-loop, transposed operands: acc[i][j] = W_frag[j] x Act_frag[i].
// D layout: batchrow = lane&15 (+16*i), feature = kgrp*4 + reg (+16*j).
// DOUBLE-buffered weights (w0/w1 = 32 regs): with RT=2 a ks-round is only
// ~8 MFMA (~40 cyc issue), far under the ~200-400 cy L2 load latency, so the
// one-ks lookahead is required. Register budget NOW has room: 32 AGPR acc +
// 32 w + 8 ax + misc ~ 90 < 128 (unlike R1-R5's 64-AGPR shape where this
// same double-buffer spilled).
// wpre holds the ks=0 fragments, preloaded before the prior barrier.
// ---------------------------------------------------------------------------
template <int KSTEPS, int NT, int JF, int RT, int ASTRIDE>
__device__ __forceinline__ void mlp_layer(const char* Abase, const char* Bbase,
                                          int laneOff, f32x4 (&acc)[RT][JF],
                                          bf16x8 (&wpre)[JF]) {
    bf16x8 w0[JF], w1[JF];
#pragma unroll
    for (int j = 0; j < JF; j++) w0[j] = wpre[j];
#pragma unroll 2
    for (int ks = 0; ks < KSTEPS; ks++) {
        if (ks + 1 < KSTEPS) {
            if ((ks & 1) == 0) {
#pragma unroll
                for (int j = 0; j < JF; j++)
                    w1[j] = *(const bf16x8*)(Bbase + (((ks + 1) * NT + j) << 10) + laneOff);
            } else {
#pragma unroll
                for (int j = 0; j < JF; j++)
                    w0[j] = *(const bf16x8*)(Bbase + (((ks + 1) * NT + j) << 10) + laneOff);
            }
        }
        bf16x8 ax[RT];
#pragma unroll
        for (int i = 0; i < RT; i++)
            ax[i] = *(const bf16x8*)(Abase + ks * 64 + i * 16 * ASTRIDE);
#pragma unroll
        for (int i = 0; i < RT; i++)
#pragma unroll
            for (int j = 0; j < JF; j++)
                acc[i][j] = __builtin_amdgcn_mfma_f32_16x16x32_bf16(
                    (ks & 1) ? w1[j] : w0[j], ax[i], acc[i][j], 0, 0, 0);
    }
}

// Transposed epilogue: lane writes 4 consecutive features (8 B) per (i,j),
// into the DESTINATION slab (dual-slab ping-pong: never the slab being read,
// so no pre-store barrier is needed). Wave wn owns features [wn*64, +64).
__device__ __forceinline__ void store_h_relu_t(const f32x4 (&acc)[2][4],
                                               char* dst, const float* bias,
                                               int wn, int lrow, int kgrp) {
#pragma unroll
    for (int j = 0; j < 4; j++) {
        int f = wn * 64 + j * 16 + kgrp * 4;
        float4 bb = *(const float4*)(bias + f);
#pragma unroll
        for (int i = 0; i < 2; i++) {
            float v0 = acc[i][j][0] + bb.x;
            float v1 = acc[i][j][1] + bb.y;
            float v2 = acc[i][j][2] + bb.z;
            float v3 = acc[i][j][3] + bb.w;
            v0 = v0 > 0.0f ? v0 : 0.0f;
            v1 = v1 > 0.0f ? v1 : 0.0f;
            v2 = v2 > 0.0f ? v2 : 0.0f;
            v3 = v3 > 0.0f ? v3 : 0.0f;
            union { __hip_bfloat162 h2[2]; uint2 u; } pk;
            pk.h2[0] = __float22bfloat162_rn(make_float2(v0, v1));
            pk.h2[1] = __float22bfloat162_rn(make_float2(v2, v3));
            *(uint2*)(dst + (i * 16 + lrow) * HSTRIDE + f * 2) = pk.u;
        }
    }
}

__device__ __forceinline__ void quat_apply3(float qx, float qy, float qz,
                                            float qw, float vx, float vy,
                                            float vz, float& ox, float& oy,
                                            float& oz) {
    float tx = 2.0f * (qy * vz - qz * vy);
    float ty = 2.0f * (qz * vx - qx * vz);
    float tz = 2.0f * (qx * vy - qy * vx);
    ox = vx + qw * tx + (qy * tz - qz * ty);
    oy = vy + qw * ty + (qz * tx - qx * tz);
    oz = vz + qw * tz + (qx * ty - qy * tx);
}

// ---------------------------------------------------------------------------
// Fused: build features + 3-layer MLP + integrate.
// 1024 blocks x 512 threads (8 waves). Block = 32 batch rows.
// LDS = 2 slabs x 33280 = 66560 B -> 2 blocks/CU (16 waves, 4/SIMD, 128-cap).
// DUAL-SLAB PING-PONG (the R10->R11 structural change): stage x->A;
// L1 reads A, writes h1->B; L2 reads B, writes h2->A; L3 reads A, writes
// delta->B (out-slot layout); integrate in place in B; copy B->global.
// Distinct read/write slabs per phase => ONE barrier per transition:
// 5 barriers vs the single-slab structure's 8. Grid = 2 generations ->
// the two CU block slots desynchronize, overlapping memory phases of one
// block with MFMA of the other. acc[2][4] = 32 AGPR -> real register
// headroom for the weight double-buffer (no spill, unlike R6/R9).
// ---------------------------------------------------------------------------
__global__ __launch_bounds__(512, 4) void fused_mlp(
    const float* __restrict__ obs, const float* __restrict__ action,
    const __hip_bfloat16* __restrict__ W1p, const float* __restrict__ b1,
    const __hip_bfloat16* __restrict__ W2p, const float* __restrict__ b2,
    const __hip_bfloat16* __restrict__ W3p, const float* __restrict__ b3,
    const float* __restrict__ dstd, const float* __restrict__ dmean,
    const float* __restrict__ state, float* __restrict__ out) {
    alignas(16) __shared__ char smem[2 * SLAB];  // 66560 B
    char* slabA = smem;
    char* slabB = smem + SLAB;
    const int tid = threadIdx.x;
    const int blk = blockIdx.x;
    const int lane = tid & 63, wn = tid >> 6;  // wn in [0,8)
    const int lrow = lane & 15, kgrp = lane >> 4;
    const int laneOff = lane * 16;

    // ---- preload L1 ks=0 weight frags: L2 latency hides under staging ----
    bf16x8 wpre[4];
#pragma unroll
    for (int j = 0; j < 4; j++)
        wpre[j] = *(const bf16x8*)((const char*)W1p + (wn << 12) + (j << 10) + laneOff);

    // ---- stage obs -> bf16 slab A (row-major, stride XSTRIDE) + features --
    {
        const float4* og = (const float4*)obs + (size_t)blk * ROWS * 75;
#pragma unroll
        for (int i = 0; i < 5; i++) {
            int f = tid + i * 512;
            if (f < ROWS * 75) {
                int row = f / 75;
                int c4 = f - row * 75;
                float4 v = og[f];
                union { __hip_bfloat162 h2[2]; uint2 u; } pk;
                pk.h2[0] = __float22bfloat162_rn(make_float2(v.x, v.y));
                pk.h2[1] = __float22bfloat162_rn(make_float2(v.z, v.w));
                *(uint2*)(slabA + row * XSTRIDE + c4 * 8) = pk.u;
            }
        }
        // quat 6d features: ROWS rows x 19 quats
#pragma unroll
        for (int i = 0; i < 2; i++) {
            int q = tid + i * 512;
            if (q < ROWS * 19) {
                int row = q / 19;
                int j = q - row * 19;
                const float* a = action + ((size_t)(blk * ROWS + row)) * 57 + j * 3;
                float rx = a[0], ry = a[1], rz = a[2];
                float ang = sqrtf(rx * rx + ry * ry + rz * rz);
                float half = 0.5f * ang;
                float s;
                if (ang < 1e-8f)
                    s = 0.5f - ang * ang * (1.0f / 48.0f);
                else
                    s = __sinf(half) / ang;
                float qx = rx * s, qy = ry * s, qz = rz * s, qw = __cosf(half);
                // flip_quat_by_w dropped: R(-q) == R(q).
                union { __hip_bfloat16 h[6]; uint u[3]; } pq;
                pq.h[0] = __float2bfloat16(1.0f - 2.0f * (qy * qy + qz * qz));
                pq.h[1] = __float2bfloat16(2.0f * (qx * qy - qz * qw));
                pq.h[2] = __float2bfloat16(2.0f * (qx * qy + qz * qw));
                pq.h[3] = __float2bfloat16(1.0f - 2.0f * (qx * qx + qz * qz));
                pq.h[4] = __float2bfloat16(2.0f * (qx * qz - qy * qw));
                pq.h[5] = __float2bfloat16(2.0f * (qy * qz + qx * qw));
                char* p = slabA + row * XSTRIDE + 600 + j * 12;
                *(uint*)p = pq.u[0];
                *(uint*)(p + 4) = pq.u[1];
                *(uint*)(p + 8) = pq.u[2];
            }
        }
        // zero pad cols 414..423
        if (tid < ROWS * 5) {
            int row = tid / 5;
            int p = tid - row * 5;
            *(uint*)(slabA + row * XSTRIDE + 828 + p * 4) = 0u;
        }
    }
    __syncthreads();  // b1: x (slab A) ready

    f32x4 acc[2][4];
    f32x4 zero4 = {0.0f, 0.0f, 0.0f, 0.0f};
#pragma unroll
    for (int i = 0; i < 2; i++)
#pragma unroll
        for (int j = 0; j < 4; j++) acc[i][j] = zero4;

    // ---- layer 1: h1 = relu(x @ W1 + b1), K=416. A=slabA -> h1=slabB ----
    mlp_layer<13, 32, 4, 2, XSTRIDE>(slabA + lrow * XSTRIDE + kgrp * 16,
                                     (const char*)W1p + (wn << 12), laneOff,
                                     acc, wpre);
    store_h_relu_t(acc, slabB, b1, wn, lrow, kgrp);
    // preload L2 ks=0 frags: latency hides under the barrier
#pragma unroll
    for (int j = 0; j < 4; j++)
        wpre[j] = *(const bf16x8*)((const char*)W2p + (wn << 12) + (j << 10) + laneOff);
    __syncthreads();  // b2: h1 (slab B) ready, slab A free

    // ---- layer 2: h2 = relu(h1 @ W2 + b2), K=512. A=slabB -> h2=slabA ----
#pragma unroll
    for (int i = 0; i < 2; i++)
#pragma unroll
        for (int j = 0; j < 4; j++) acc[i][j] = zero4;
    mlp_layer<16, 32, 4, 2, HSTRIDE>(slabB + lrow * HSTRIDE + kgrp * 16,
                                     (const char*)W2p + (wn << 12), laneOff,
                                     acc, wpre);
    store_h_relu_t(acc, slabA, b2, wn, lrow, kgrp);
    // preload L3 ks=0 frag
    const char* Bb3 = (const char*)W3p + (wn << 10);
    bf16x8 c0 = *(const bf16x8*)(Bb3 + laneOff);
    __syncthreads();  // b3: h2 (slab A) ready, slab B free

    // ---- layer 3: delta = (h2 @ W3 + b3) * std + mean, N=120(128).
    //      reads slab A; writes scaled delta straight into slab B in the
    //      out-slot layout: slabB f32 [32 x 260],
    //      (row, feature f) -> [row*260 + (f/6)*13 + f%6] ----
    f32x4 a3[2];
#pragma unroll
    for (int i = 0; i < 2; i++) a3[i] = zero4;
    {
        const char* Ab = slabA + lrow * HSTRIDE + kgrp * 16;
        bf16x8 c1;
#pragma unroll 2
        for (int ks = 0; ks < 16; ks++) {
            if (ks + 1 < 16) {
                if ((ks & 1) == 0)
                    c1 = *(const bf16x8*)(Bb3 + ((ks + 1) << 13) + laneOff);
                else
                    c0 = *(const bf16x8*)(Bb3 + ((ks + 1) << 13) + laneOff);
            }
            bf16x8 ax[2];
#pragma unroll
            for (int i = 0; i < 2; i++)
                ax[i] = *(const bf16x8*)(Ab + ks * 64 + i * 16 * HSTRIDE);
#pragma unroll
            for (int i = 0; i < 2; i++)
                a3[i] = __builtin_amdgcn_mfma_f32_16x16x32_bf16(
                    (ks & 1) ? c1 : c0, ax[i], a3[i], 0, 0, 0);
        }
    }
    float* dl = (float*)slabB;
    {
        int f = wn * 16 + kgrp * 4;
        if (f < 120) {
            float4 bb = *(const float4*)(b3 + f);
            float4 sc = *(const float4*)(dstd + f);
            float4 mn = *(const float4*)(dmean + f);
            int bo0 = (f + 0) / 6, o0 = bo0 * 13 + (f + 0) - bo0 * 6;
            int bo1 = (f + 1) / 6, o1 = bo1 * 13 + (f + 1) - bo1 * 6;
            int bo2 = (f + 2) / 6, o2 = bo2 * 13 + (f + 2) - bo2 * 6;
            int bo3 = (f + 3) / 6, o3 = bo3 * 13 + (f + 3) - bo3 * 6;
#pragma unroll
            for (int i = 0; i < 2; i++) {
                float* rs = dl + (i * 16 + lrow) * 260;
                rs[o0] = (a3[i][0] + bb.x) * sc.x + mn.x;
                rs[o1] = (a3[i][1] + bb.y) * sc.y + mn.y;
                rs[o2] = (a3[i][2] + bb.z) * sc.z + mn.z;
                rs[o3] = (a3[i][3] + bb.w) * sc.w + mn.w;
            }
        }
    }
    __syncthreads();  // b4: delta (slab B) ready

    // ---- integrate in place in slab B: thread owns slot (lr, body); reads
    //      its 6 delta floats, loads state direct, overwrites slot with 13
    //      outputs. Same-thread RAW only -> no cross-thread hazard; no
    //      persistent register arrays -> no spill. ----
#pragma unroll
    for (int it = 0; it < 2; it++) {
        int idx = tid + it * 512;
        if (idx < ROWS * 20) {
            int lr = idx / 20;
            int body = idx - lr * 20;
            const float* sb = state + ((size_t)(blk * ROWS + lr)) * 260 + body * 13;
            f4u s0 = *(const f4u*)sb;
            f4u s1 = *(const f4u*)(sb + 4);
            f4u s2 = *(const f4u*)(sb + 8);
            float s12 = sb[12];
            f4u rq = *(const f4u*)(state + ((size_t)(blk * ROWS + lr)) * 260 + 3);

            float* slot = dl + lr * 260 + body * 13;
            float d0 = slot[0], d1 = slot[1], d2 = slot[2];
            float d3 = slot[3], d4 = slot[4], d5 = slot[5];

            float lx, ly, lz, ax, ay, az;
            quat_apply3(rq.x, rq.y, rq.z, rq.w, d0, d1, d2, lx, ly, lz);
            quat_apply3(rq.x, rq.y, rq.z, rq.w, d3, d4, d5, ax, ay, az);

            float vx = s1.w + lx, vy = s2.x + ly, vz = s2.y + lz;
            float wx = s2.z + ax, wy = s2.w + ay, wz = s12 + az;
            float px = s0.x + vx * DT, py = s0.y + vy * DT, pz = s0.z + vz * DT;

            float rx = s0.w, ry = s1.x, rz = s1.y, rw = s1.z;
            float dqx = rw * wx + (wy * rz - wz * ry);
            float dqy = rw * wy + (wz * rx - wx * rz);
            float dqz = rw * wz + (wx * ry - wy * rx);
            float dqw = -(wx * rx + wy * ry + wz * rz);
            float h = 0.5f * DT;
            float nx = rx + h * dqx, ny = ry + h * dqy, nz = rz + h * dqz,
                  nw = rw + h * dqw;
            float inv = 1.0f / sqrtf(nx * nx + ny * ny + nz * nz + nw * nw);

            slot[0] = px;
            slot[1] = py;
            slot[2] = pz;
            slot[3] = nx * inv;
            slot[4] = ny * inv;
            slot[5] = nz * inv;
            slot[6] = nw * inv;
            slot[7] = vx;
            slot[8] = vy;
            slot[9] = vz;
            slot[10] = wx;
            slot[11] = wy;
            slot[12] = wz;
        }
    }
    __syncthreads();  // b5: out rows (slab B) ready

    // ---- coalesced copy slab B -> global: ROWS x 65 float4, contiguous ----
    {
        float4* og = (float4*)(out + (size_t)blk * ROWS * 260);
#pragma unroll
        for (int i = 0; i < 5; i++) {
            int f = tid + i * 512;
            if (f < ROWS * 65) {
                og[f] = *(const float4*)(slabB + f * 16);
            }
        }
    }
}

// ---------------------------------------------------------------------------
extern "C" void kernel_launch(void* const* d_in, const int* in_sizes, int n_in,
                              void* d_out, int out_size, void* d_ws,
                              size_t ws_size, hipStream_t stream) {
    const float* state = (const float*)d_in[0];
    const float* action = (const float*)d_in[1];
    const float* obs = (const float*)d_in[2];
    const float* W1 = (const float*)d_in[3];
    const float* b1 = (const float*)d_in[4];
    const float* W2 = (const float*)d_in[5];
    const float* b2 = (const float*)d_in[6];
    const float* W3 = (const float*)d_in[7];
    const float* b3 = (const float*)d_in[8];
    const float* dmean = (const float*)d_in[9];
    const float* dstd = (const float*)d_in[10];
    float* out = (float*)d_out;
    char* ws = (char*)d_ws;

    const int B = in_sizes[1] / 57;  // 32768

    __hip_bfloat16* W1p = (__hip_bfloat16*)(ws);           // 13*32 frags
    __hip_bfloat16* W2p = (__hip_bfloat16*)(ws + 425984);  // 16*32 frags
    __hip_bfloat16* W3p = (__hip_bfloat16*)(ws + 950272);  // 16*8 frags

    prep_weights<<<2112, 256, 0, stream>>>(W1, W2, W3, W1p, W2p, W3p);
    fused_mlp<<<B / ROWS, 512, 0, stream>>>(obs, action, W1p, b1, W2p, b2,
                                            W3p, b3, dstd, dmean, state, out);
}

// Round 12
// 162.382 us; speedup vs baseline: 1.0610x; 1.0610x over previous
//
#include <hip/hip_runtime.h>
#include <hip/hip_bf16.h>
#include <math.h>

#define DT (1.0f / 60.0f)

typedef __bf16 bf16x8 __attribute__((ext_vector_type(8)));
typedef float f32x4 __attribute__((ext_vector_type(4)));

#define XSTRIDE 848   // 424 bf16 cols: 212 dwords % 8 == 4 -> 2-way (free)
#define HSTRIDE 1040  // 520 bf16 cols: 260 dwords % 8 == 4 -> 2-way (free)
#define DLSTRIDE 124  // fp32 delta slab row stride (dwords)

// 4-byte-aligned float4 for vectorized loads of 13-float-strided state
struct __attribute__((packed)) f4u {
    float x, y, z, w;
};

// ---------------------------------------------------------------------------
// Weight prep into MFMA-fragment-packed layout.
// frag(ks, nt) is 1KB contiguous; lane l (lrow=l&15, kgrp=l>>4) reads bytes
// [l*16, +16) = W[k = ks*32 + kgrp*8 + e][n = nt*16 + lrow], e=0..7.
// ---------------------------------------------------------------------------
__global__ __launch_bounds__(256) void prep_weights(
    const float* __restrict__ W1, const float* __restrict__ W2,
    const float* __restrict__ W3, __hip_bfloat16* __restrict__ W1p,
    __hip_bfloat16* __restrict__ W2p, __hip_bfloat16* __restrict__ W3p) {
    int idx = blockIdx.x * 256 + threadIdx.x;
    if (idx < 212992) {  // W1p: KS=13, NT=32 (K pad 416, N=512)
        int d = idx;
        int e = d & 7, l = (d >> 3) & 63, t = d >> 9;
        int nt = t & 31, ks = t >> 5;
        int n = nt * 16 + (l & 15);
        int k = ks * 32 + (l >> 4) * 8 + e;
        W1p[d] = __float2bfloat16(k < 414 ? W1[k * 512 + n] : 0.0f);
        return;
    }
    idx -= 212992;
    if (idx < 262144) {  // W2p: KS=16, NT=32
        int d = idx;
        int e = d & 7, l = (d >> 3) & 63, t = d >> 9;
        int nt = t & 31, ks = t >> 5;
        int n = nt * 16 + (l & 15);
        int k = ks * 32 + (l >> 4) * 8 + e;
        W2p[d] = __float2bfloat16(W2[k * 512 + n]);
        return;
    }
    idx -= 262144;
    if (idx < 65536) {  // W3p: KS=16, NT=8 (N pad 128)
        int d = idx;
        int e = d & 7, l = (d >> 3) & 63, t = d >> 9;
        int nt = t & 7, ks = t >> 3;
        int n = nt * 16 + (l & 15);
        int k = ks * 32 + (l >> 4) * 8 + e;
        W3p[d] = __float2bfloat16(n < 120 ? W3[k * 120 + n] : 0.0f);
    }
}

// ---------------------------------------------------------------------------
// K-loop, transposed operands: acc[i][j] = W_frag[j] x Act_frag[i].
// D layout: batchrow = lane&15 (+16*i), feature = kgrp*4 + reg (+16*j).
// SINGLE-buffered weights (w[JF] = 16 regs at JF=4): R7-verified — the
// double-buffer's 32 regs overflowed the 128-cap (64 AGPR acc + 64 arch)
// and spilled ~11 MB/launch to scratch. Load latency is covered by MFMA
// issue contention from 4 waves/SIMD (~310 cy/round vs ~200-400 cy L2).
// wpre holds the ks=0 fragments, preloaded before the prior barrier.
// ---------------------------------------------------------------------------
template <int KSTEPS, int NT, int JF, int ASTRIDE>
__device__ __forceinline__ void mlp_layer(const char* Abase, const char* Bbase,
                                          int laneOff, f32x4 (&acc)[4][JF],
                                          bf16x8 (&wpre)[JF]) {
    bf16x8 w[JF];
#pragma unroll
    for (int j = 0; j < JF; j++) w[j] = wpre[j];
#pragma unroll 2
    for (int ks = 0; ks < KSTEPS; ks++) {
        bf16x8 ax[4];
#pragma unroll
        for (int i = 0; i < 4; i++)
            ax[i] = *(const bf16x8*)(Abase + ks * 64 + i * 16 * ASTRIDE);
#pragma unroll
        for (int i = 0; i < 4; i++)
#pragma unroll
            for (int j = 0; j < JF; j++)
                acc[i][j] = __builtin_amdgcn_mfma_f32_16x16x32_bf16(
                    w[j], ax[i], acc[i][j], 0, 0, 0);
        if (ks + 1 < KSTEPS) {
#pragma unroll
            for (int j = 0; j < JF; j++)
                w[j] = *(const bf16x8*)(Bbase + (((ks + 1) * NT + j) << 10) + laneOff);
        }
    }
}

// Transposed epilogue: lane writes 4 consecutive features (8 B) per (i,j).
// Wave wn owns features [wn*64, +64).
__device__ __forceinline__ void store_h_relu_t(const f32x4 (&acc)[4][4],
                                               char* smem, const float* bias,
                                               int wn, int lrow, int kgrp) {
#pragma unroll
    for (int j = 0; j < 4; j++) {
        int f = wn * 64 + j * 16 + kgrp * 4;
        float4 bb = *(const float4*)(bias + f);
#pragma unroll
        for (int i = 0; i < 4; i++) {
            float v0 = acc[i][j][0] + bb.x;
            float v1 = acc[i][j][1] + bb.y;
            float v2 = acc[i][j][2] + bb.z;
            float v3 = acc[i][j][3] + bb.w;
            v0 = v0 > 0.0f ? v0 : 0.0f;
            v1 = v1 > 0.0f ? v1 : 0.0f;
            v2 = v2 > 0.0f ? v2 : 0.0f;
            v3 = v3 > 0.0f ? v3 : 0.0f;
            union { __hip_bfloat162 h2[2]; uint2 u; } pk;
            pk.h2[0] = __float22bfloat162_rn(make_float2(v0, v1));
            pk.h2[1] = __float22bfloat162_rn(make_float2(v2, v3));
            *(uint2*)(smem + (i * 16 + lrow) * HSTRIDE + f * 2) = pk.u;
        }
    }
}

__device__ __forceinline__ void quat_apply3(float qx, float qy, float qz,
                                            float qw, float vx, float vy,
                                            float vz, float& ox, float& oy,
                                            float& oz) {
    float tx = 2.0f * (qy * vz - qz * vy);
    float ty = 2.0f * (qz * vx - qx * vz);
    float tz = 2.0f * (qx * vy - qy * vx);
    ox = vx + qw * tx + (qy * tz - qz * ty);
    oy = vy + qw * ty + (qz * tx - qx * tz);
    oz = vz + qw * tz + (qx * ty - qy * tx);
}

// ---------------------------------------------------------------------------
// Fused: build features + 3-layer MLP + integrate (coalesced out via LDS).
// 512 blocks x 512 threads (8 waves). Block = 64 batch rows in LDS.
// LDS 66560 B -> 2 blocks/CU -> 16 waves/CU (4 waves/SIMD).
// FINAL STRUCTURE (session optimum, measured): 64 rows x 512 thr x 2
// blocks/CU. Larger blocks (R2: 128 rows) lose cross-block overlap (+13us);
// smaller (R11: 32 rows) halve MFMA per weight load -> load-latency-bound
// (+13us). Single-buffered weights are mandatory at the 128-reg cap
// (double-buffer spills ~11 MB, R1-R5). Remaining ceiling is the serialized
// phase-chain latency; all pipes <25%, no spill, conflicts hidden.
// ---------------------------------------------------------------------------
__global__ __launch_bounds__(512, 4) void fused_mlp(
    const float* __restrict__ obs, const float* __restrict__ action,
    const __hip_bfloat16* __restrict__ W1p, const float* __restrict__ b1,
    const __hip_bfloat16* __restrict__ W2p, const float* __restrict__ b2,
    const __hip_bfloat16* __restrict__ W3p, const float* __restrict__ b3,
    const float* __restrict__ dstd, const float* __restrict__ dmean,
    const float* __restrict__ state, float* __restrict__ out) {
    alignas(16) __shared__ char smem[64 * HSTRIDE];  // 66560 B
    const int tid = threadIdx.x;
    const int blk = blockIdx.x;
    const int lane = tid & 63, wn = tid >> 6;  // wn in [0,8)
    const int lrow = lane & 15, kgrp = lane >> 4;
    const int laneOff = lane * 16;

    // ---- preload L1 ks=0 weight frags: L2 latency hides under staging ----
    bf16x8 wpre[4];
#pragma unroll
    for (int j = 0; j < 4; j++)
        wpre[j] = *(const bf16x8*)((const char*)W1p + (wn << 12) + (j << 10) + laneOff);

    // ---- stage obs -> bf16 LDS (stride XSTRIDE) + fused feature build ----
    {
        const float4* og = (const float4*)obs + (size_t)blk * 64 * 75;
#pragma unroll
        for (int i = 0; i < 10; i++) {
            int f = tid + i * 512;
            if (f < 4800) {
                int row = f / 75;
                int c4 = f - row * 75;
                float4 v = og[f];
                union { __hip_bfloat162 h2[2]; uint2 u; } pk;
                pk.h2[0] = __float22bfloat162_rn(make_float2(v.x, v.y));
                pk.h2[1] = __float22bfloat162_rn(make_float2(v.z, v.w));
                *(uint2*)(smem + row * XSTRIDE + c4 * 8) = pk.u;
            }
        }
        // quat 6d features: 64 rows x 19 quats
#pragma unroll
        for (int i = 0; i < 3; i++) {
            int q = tid + i * 512;
            if (q < 1216) {
                int row = q / 19;
                int j = q - row * 19;
                const float* a = action + ((size_t)(blk * 64 + row)) * 57 + j * 3;
                float rx = a[0], ry = a[1], rz = a[2];
                float ang = sqrtf(rx * rx + ry * ry + rz * rz);
                float half = 0.5f * ang;
                float s;
                if (ang < 1e-8f)
                    s = 0.5f - ang * ang * (1.0f / 48.0f);
                else
                    s = __sinf(half) / ang;
                float qx = rx * s, qy = ry * s, qz = rz * s, qw = __cosf(half);
                // flip_quat_by_w dropped: R(-q) == R(q).
                union { __hip_bfloat16 h[6]; uint u[3]; } pq;
                pq.h[0] = __float2bfloat16(1.0f - 2.0f * (qy * qy + qz * qz));
                pq.h[1] = __float2bfloat16(2.0f * (qx * qy - qz * qw));
                pq.h[2] = __float2bfloat16(2.0f * (qx * qy + qz * qw));
                pq.h[3] = __float2bfloat16(1.0f - 2.0f * (qx * qx + qz * qz));
                pq.h[4] = __float2bfloat16(2.0f * (qx * qz - qy * qw));
                pq.h[5] = __float2bfloat16(2.0f * (qy * qz + qx * qw));
                char* p = smem + row * XSTRIDE + 600 + j * 12;
                *(uint*)p = pq.u[0];
                *(uint*)(p + 4) = pq.u[1];
                *(uint*)(p + 8) = pq.u[2];
            }
        }
        // zero pad cols 414..423
        if (tid < 320) {
            int row = tid / 5;
            int p = tid - row * 5;
            *(uint*)(smem + row * XSTRIDE + 828 + p * 4) = 0u;
        }
    }
    __syncthreads();  // x slab ready

    f32x4 acc[4][4];
    f32x4 zero4 = {0.0f, 0.0f, 0.0f, 0.0f};
#pragma unroll
    for (int i = 0; i < 4; i++)
#pragma unroll
        for (int j = 0; j < 4; j++) acc[i][j] = zero4;

    // ---- layer 1: h1 = relu(x @ W1 + b1), K=416 ----
    mlp_layer<13, 32, 4, XSTRIDE>(smem + lrow * XSTRIDE + kgrp * 16,
                                  (const char*)W1p + (wn << 12), laneOff, acc,
                                  wpre);
    // preload L2 ks=0 frags: latency hides under h1 store + 2 barriers
#pragma unroll
    for (int j = 0; j < 4; j++)
        wpre[j] = *(const bf16x8*)((const char*)W2p + (wn << 12) + (j << 10) + laneOff);
    __syncthreads();
    store_h_relu_t(acc, smem, b1, wn, lrow, kgrp);
    __syncthreads();

    // ---- layer 2: h2 = relu(h1 @ W2 + b2), K=512 ----
#pragma unroll
    for (int i = 0; i < 4; i++)
#pragma unroll
        for (int j = 0; j < 4; j++) acc[i][j] = zero4;
    mlp_layer<16, 32, 4, HSTRIDE>(smem + lrow * HSTRIDE + kgrp * 16,
                                  (const char*)W2p + (wn << 12), laneOff, acc,
                                  wpre);
    // preload L3 ks=0 frag: latency hides under h2 store + 2 barriers
    const char* Bb3 = (const char*)W3p + (wn << 10);
    bf16x8 c0 = *(const bf16x8*)(Bb3 + laneOff);
    __syncthreads();
    store_h_relu_t(acc, smem, b2, wn, lrow, kgrp);
    __syncthreads();

    // ---- prefetch integrate state into registers (hidden under layer 3) ---
    f4u ps0[3], ps1[3], ps2[3], prq[3];
    float ps12[3];
#pragma unroll
    for (int it = 0; it < 3; it++) {
        int idx = tid + it * 512;
        if (idx < 1280) {
            int lr = idx / 20;
            int body = idx - lr * 20;
            const float* sb = state + ((size_t)(blk * 64 + lr)) * 260 + body * 13;
            const float* rq = state + ((size_t)(blk * 64 + lr)) * 260 + 3;
            ps0[it] = *(const f4u*)sb;
            ps1[it] = *(const f4u*)(sb + 4);
            ps2[it] = *(const f4u*)(sb + 8);
            ps12[it] = sb[12];
            prq[it] = *(const f4u*)rq;
        }
    }

    // ---- layer 3: delta = (h2 @ W3 + b3) * std + mean, N=120(128) ----
    // wave wn owns features [wn*16, +16): one frag, a3[bt 0..3]
    f32x4 a3[4];
#pragma unroll
    for (int i = 0; i < 4; i++) a3[i] = zero4;
    {
        const char* Ab = smem + lrow * HSTRIDE + kgrp * 16;
        bf16x8 c1;
#pragma unroll 2
        for (int ks = 0; ks < 16; ks++) {
            if (ks + 1 < 16) {
                if ((ks & 1) == 0)
                    c1 = *(const bf16x8*)(Bb3 + ((ks + 1) << 13) + laneOff);
                else
                    c0 = *(const bf16x8*)(Bb3 + ((ks + 1) << 13) + laneOff);
            }
            bf16x8 ax[4];
#pragma unroll
            for (int i = 0; i < 4; i++)
                ax[i] = *(const bf16x8*)(Ab + ks * 64 + i * 16 * HSTRIDE);
#pragma unroll
            for (int i = 0; i < 4; i++)
                a3[i] = __builtin_amdgcn_mfma_f32_16x16x32_bf16(
                    (ks & 1) ? c1 : c0, ax[i], a3[i], 0, 0, 0);
        }
    }
    __syncthreads();  // all waves done reading h2; smem free for delta

    // delta -> LDS fp32 [64 x DLSTRIDE]: lane writes float4 (4 features)
    float* dl = (float*)smem;
    {
        int f = wn * 16 + kgrp * 4;
        if (f < 120) {
            float4 bb = *(const float4*)(b3 + f);
            float4 sc = *(const float4*)(dstd + f);
            float4 mn = *(const float4*)(dmean + f);
#pragma unroll
            for (int i = 0; i < 4; i++) {
                int row = i * 16 + lrow;
                float4 dv;
                dv.x = (a3[i][0] + bb.x) * sc.x + mn.x;
                dv.y = (a3[i][1] + bb.y) * sc.y + mn.y;
                dv.z = (a3[i][2] + bb.z) * sc.z + mn.z;
                dv.w = (a3[i][3] + bb.w) * sc.w + mn.w;
                *(float4*)(dl + row * DLSTRIDE + f) = dv;
            }
        }
    }
    __syncthreads();

    // ---- integrate into REGISTERS (no global stores yet) ----
    float ov[3][13];
#pragma unroll
    for (int it = 0; it < 3; it++) {
        int idx = tid + it * 512;
        if (idx < 1280) {
            int lr = idx / 20;
            int body = idx - lr * 20;
            float qx = prq[it].x, qy = prq[it].y, qz = prq[it].z, qw = prq[it].w;
            const float* d = dl + lr * DLSTRIDE + body * 6;

            float lx, ly, lz, ax, ay, az;
            quat_apply3(qx, qy, qz, qw, d[0], d[1], d[2], lx, ly, lz);
            quat_apply3(qx, qy, qz, qw, d[3], d[4], d[5], ax, ay, az);

            float vx = ps1[it].w + lx, vy = ps2[it].x + ly, vz = ps2[it].y + lz;
            float wx = ps2[it].z + ax, wy = ps2[it].w + ay, wz = ps12[it] + az;
            float px = ps0[it].x + vx * DT, py = ps0[it].y + vy * DT,
                  pz = ps0[it].z + vz * DT;

            float rx = ps0[it].w, ry = ps1[it].x, rz = ps1[it].y, rw = ps1[it].z;
            float dqx = rw * wx + (wy * rz - wz * ry);
            float dqy = rw * wy + (wz * rx - wx * rz);
            float dqz = rw * wz + (wx * ry - wy * rx);
            float dqw = -(wx * rx + wy * ry + wz * rz);
            float h = 0.5f * DT;
            float nx = rx + h * dqx, ny = ry + h * dqy, nz = rz + h * dqz,
                  nw = rw + h * dqw;
            float inv = 1.0f / sqrtf(nx * nx + ny * ny + nz * nz + nw * nw);

            ov[it][0] = px;
            ov[it][1] = py;
            ov[it][2] = pz;
            ov[it][3] = nx * inv;
            ov[it][4] = ny * inv;
            ov[it][5] = nz * inv;
            ov[it][6] = nw * inv;
            ov[it][7] = vx;
            ov[it][8] = vy;
            ov[it][9] = vz;
            ov[it][10] = wx;
            ov[it][11] = wy;
            ov[it][12] = wz;
        }
    }
    __syncthreads();  // dl reads done; slab reusable as out-stage

    // ---- stage out rows in LDS [64 x 260 fp32] ----
    // addr/4 = row*260 + body*13 + k: stride 13 (odd) -> conflict-free spread
#pragma unroll
    for (int it = 0; it < 3; it++) {
        int idx = tid + it * 512;
        if (idx < 1280) {
            int lr = idx / 20;
            int body = idx - lr * 20;
            float* dst = (float*)(smem + lr * 1040 + body * 52);
#pragma unroll
            for (int k = 0; k < 13; k++) dst[k] = ov[it][k];
        }
    }
    __syncthreads();

    // ---- coalesced copy LDS -> global: 64 rows x 65 float4, contiguous ----
    {
        float4* og = (float4*)(out + (size_t)blk * 64 * 260);
#pragma unroll
        for (int i = 0; i < 9; i++) {
            int f = tid + i * 512;
            if (f < 4160) {
                og[f] = *(const float4*)(smem + f * 16);
            }
        }
    }
}

// ---------------------------------------------------------------------------
extern "C" void kernel_launch(void* const* d_in, const int* in_sizes, int n_in,
                              void* d_out, int out_size, void* d_ws,
                              size_t ws_size, hipStream_t stream) {
    const float* state = (const float*)d_in[0];
    const float* action = (const float*)d_in[1];
    const float* obs = (const float*)d_in[2];
    const float* W1 = (const float*)d_in[3];
    const float* b1 = (const float*)d_in[4];
    const float* W2 = (const float*)d_in[5];
    const float* b2 = (const float*)d_in[6];
    const float* W3 = (const float*)d_in[7];
    const float* b3 = (const float*)d_in[8];
    const float* dmean = (const float*)d_in[9];
    const float* dstd = (const float*)d_in[10];
    float* out = (float*)d_out;
    char* ws = (char*)d_ws;

    const int B = in_sizes[1] / 57;  // 32768

    __hip_bfloat16* W1p = (__hip_bfloat16*)(ws);           // 13*32 frags
    __hip_bfloat16* W2p = (__hip_bfloat16*)(ws + 425984);  // 16*32 frags
    __hip_bfloat16* W3p = (__hip_bfloat16*)(ws + 950272);  // 16*8 frags

    prep_weights<<<2112, 256, 0, stream>>>(W1, W2, W3, W1p, W2p, W3p);
    fused_mlp<<<B / 64, 512, 0, stream>>>(obs, action, W1p, b1, W2p, b2, W3p,
                                          b3, dstd, dmean, state, out);
}